// Round 5
// baseline (3872.905 us; speedup 1.0000x reference)
//
#include <hip/hip_runtime.h>

// OffsetMSE: min over s in [1,95] of  sum_b sum_{t<L-s} (p[b,t+s]-q[b,t])^2 / (B*(L-s))
// num(s) = (TotPP - HeadPP(s)) + (TotQQ - TailQQ(s)) - 2*C(s),
// C(s) = sum_b sum_t p_pad[t+s]*q[t]   (1 FMA per element, zero-pad handles mask).
//
// Layout: 4096 blocks (16 batches x 256 t-tiles of 4096), 512 threads = 8 waves.
// Wave w owns shifts s = 1+12w .. 12+12w; lane owns 4 t-words per sub-chunk.
// All LDS reads and global q reads are stride-1 across lanes (conflict-free,
// fully coalesced). pp computed during staging (P read exactly once).
// 16 sub-chunks of 256 words keep live VGPRs ~45 (< 64 cap at 8 waves/EU).

#define LROW   (1 << 20)
#define NBATCH 16
#define TBLK   4096
#define NTH    512
#define PWORDS (TBLK + 96)   // staged p words: global t0 .. t0+4191
#define NSLOT  32
#define SLOTW  128           // ws layout: [slot][1..96]=C(s), [100]=pp, [101]=qq

__global__ __launch_bounds__(NTH, 8)
void corr_kernel(const float* __restrict__ P, const float* __restrict__ Q,
                 float* __restrict__ ws) {
    __shared__ float ldsP[PWORDS];
    __shared__ float red[96];
    __shared__ float redp[8];

    const int b    = blockIdx.x >> 8;
    const int tile = blockIdx.x & 255;
    const int t0   = tile * TBLK;
    const float* prow = P + (size_t)b * LROW;
    const float* qrow = Q + (size_t)b * LROW;
    const int tid = threadIdx.x;

    // ---- stage p[t0 .. t0+4191] -> LDS (stride-1 float4), fused TotPP partial ----
    float pp = 0.f;
    for (int k = tid; k < PWORDS / 4; k += NTH) {
        const int gbase = t0 + 4 * k;
        float4 v;
        if (gbase + 3 < LROW) {
            v = *reinterpret_cast<const float4*>(prow + gbase);
        } else {
            v.x = (gbase + 0 < LROW) ? prow[gbase + 0] : 0.f;
            v.y = (gbase + 1 < LROW) ? prow[gbase + 1] : 0.f;
            v.z = (gbase + 2 < LROW) ? prow[gbase + 2] : 0.f;
            v.w = (gbase + 3 < LROW) ? prow[gbase + 3] : 0.f;
        }
        *reinterpret_cast<float4*>(&ldsP[4 * k]) = v;
        if (k < TBLK / 4)   // pp over exactly [t0, t0+4096)
            pp = fmaf(v.x, v.x, fmaf(v.y, v.y, fmaf(v.z, v.z, fmaf(v.w, v.w, pp))));
    }
    __syncthreads();

    const int w  = tid >> 6;        // wave = shift class, s = 1+12w+j
    const int l  = tid & 63;
    const int sb = 12 * w;
    const int lw = 4 * l;

    float acc[12];
    #pragma unroll
    for (int j = 0; j < 12; ++j) acc[j] = 0.f;
    float qq = 0.f;

    for (int sc = 0; sc < 16; ++sc) {
        const int tb = sc * 256;

        // q: one stride-1-coalesced float4 load per lane
        const float4 q0 = *reinterpret_cast<const float4*>(qrow + t0 + tb + lw);

        // p window: 4x stride-1 ds_read_b128 across lanes, i0 mult of 4
        const int i0 = tb + lw + sb;
        const float4 W0 = *reinterpret_cast<const float4*>(&ldsP[i0 +  0]);
        const float4 W1 = *reinterpret_cast<const float4*>(&ldsP[i0 +  4]);
        const float4 W2 = *reinterpret_cast<const float4*>(&ldsP[i0 +  8]);
        const float4 W3 = *reinterpret_cast<const float4*>(&ldsP[i0 + 12]);

        if (w == 0) {   // TotQQ once (wave-uniform branch)
            qq = fmaf(q0.x, q0.x, fmaf(q0.y, q0.y, fmaf(q0.z, q0.z, fmaf(q0.w, q0.w, qq))));
        }

        const float wa[16] = {W0.x,W0.y,W0.z,W0.w, W1.x,W1.y,W1.z,W1.w,
                              W2.x,W2.y,W2.z,W2.w, W3.x,W3.y,W3.z,W3.w};
        const float qa[4] = {q0.x, q0.y, q0.z, q0.w};

        // p global idx = t0 + (tb+lw+r) + s,  s = 1+sb+j  -> lds idx i0 + j+r+1
        #pragma unroll
        for (int j = 0; j < 12; ++j) {
            float a = acc[j];
            #pragma unroll
            for (int r = 0; r < 4; ++r) a = fmaf(wa[j + r + 1], qa[r], a);
            acc[j] = a;
        }
    }

    // ---- reductions: full 64-lane butterflies ----
    #pragma unroll
    for (int j = 0; j < 12; ++j) {
        float v = acc[j];
        v += __shfl_xor(v, 1);  v += __shfl_xor(v, 2);  v += __shfl_xor(v, 4);
        v += __shfl_xor(v, 8);  v += __shfl_xor(v, 16); v += __shfl_xor(v, 32);
        if (l == 0) red[sb + j] = v;
    }
    {
        float v = pp;
        v += __shfl_xor(v, 1);  v += __shfl_xor(v, 2);  v += __shfl_xor(v, 4);
        v += __shfl_xor(v, 8);  v += __shfl_xor(v, 16); v += __shfl_xor(v, 32);
        if (l == 0) redp[w] = v;
    }
    if (w == 0) {
        float v = qq;
        v += __shfl_xor(v, 1);  v += __shfl_xor(v, 2);  v += __shfl_xor(v, 4);
        v += __shfl_xor(v, 8);  v += __shfl_xor(v, 16); v += __shfl_xor(v, 32);
        qq = v;                 // lane 0 holds tile TotQQ
    }
    __syncthreads();

    float* srow = ws + (size_t)(blockIdx.x & (NSLOT - 1)) * SLOTW;
    if (tid < 96) {
        atomicAdd(&srow[1 + tid], red[tid]);
    } else if (tid == 96) {
        float s = 0.f;
        #pragma unroll
        for (int k = 0; k < 8; ++k) s += redp[k];
        atomicAdd(&srow[100], s);
    }
    if (tid == 0) atomicAdd(&srow[101], qq);
}

__global__ void minloss_kernel(const float* __restrict__ P, const float* __restrict__ Q,
                               const float* __restrict__ ws, float* __restrict__ out) {
    __shared__ float hp[96], tq[96], lossbuf[96];
    __shared__ float tots[2];
    const int tid = threadIdx.x;   // 128 threads
    if (tid < 95) {
        float s1 = 0.f, s2 = 0.f;
        #pragma unroll
        for (int b = 0; b < NBATCH; ++b) {
            const float pv = P[(size_t)b * LROW + tid];
            s1 = fmaf(pv, pv, s1);
            const float qv = Q[(size_t)b * LROW + (LROW - 1 - tid)];
            s2 = fmaf(qv, qv, s2);
        }
        hp[tid] = s1;   // sum_b p[u=tid]^2
        tq[tid] = s2;   // sum_b q[L-1-tid]^2
    } else if (tid == 96) {
        float s = 0.f;
        for (int k = 0; k < NSLOT; ++k) s += ws[k * SLOTW + 100];
        tots[0] = s;    // TotPP
    } else if (tid == 97) {
        float s = 0.f;
        for (int k = 0; k < NSLOT; ++k) s += ws[k * SLOTW + 101];
        tots[1] = s;    // TotQQ
    }
    __syncthreads();
    if (tid >= 1 && tid <= 95) {
        float C = 0.f;
        for (int k = 0; k < NSLOT; ++k) C += ws[k * SLOTW + tid];
        float head = 0.f, tail = 0.f;
        for (int u = 0; u < tid; ++u) { head += hp[u]; tail += tq[u]; }
        const float num = (tots[0] - head) + (tots[1] - tail) - 2.f * C;
        lossbuf[tid] = num / (16.f * (float)(LROW - tid));
    }
    __syncthreads();
    if (tid == 0) {
        float m = lossbuf[1];
        for (int s = 2; s <= 95; ++s) m = fminf(m, lossbuf[s]);
        out[0] = m;
    }
}

extern "C" void kernel_launch(void* const* d_in, const int* in_sizes, int n_in,
                              void* d_out, int out_size, void* d_ws, size_t ws_size,
                              hipStream_t stream) {
    const float* P = (const float*)d_in[0];   // predict
    const float* Q = (const float*)d_in[1];   // target
    float* ws = (float*)d_ws;

    hipMemsetAsync(d_ws, 0, NSLOT * SLOTW * sizeof(float), stream);
    corr_kernel<<<NBATCH * (LROW / TBLK), NTH, 0, stream>>>(P, Q, ws);
    minloss_kernel<<<1, 128, 0, stream>>>(P, Q, ws, (float*)d_out);
}

// Round 6
// 2684.275 us; speedup vs baseline: 1.4428x; 1.4428x over previous
//
#include <hip/hip_runtime.h>

// OffsetMSE: min over s in [1,95] of  sum_b sum_{t<L-s} (p[b,t+s]-q[b,t])^2 / (B*(L-s))
// num(s) = (TotPP - HeadPP(s)) + (TotQQ - TailQQ(s)) - 2*C(s),
// C(s) = sum_b sum_t p_pad[t+s]*q[t]   (1 FMA per element, zero-pad handles mask).
//
// Layout: 4096 blocks (16 batches x 256 t-tiles of 4096), 512 threads = 8 waves.
// Wave w owns shifts s = 1+12w .. 12+12w; lane owns 4 t-words per sub-chunk.
// All LDS reads and global q reads are stride-1 across lanes (conflict-free,
// fully coalesced). pp computed during staging (P read exactly once).
//
// __launch_bounds__(512, 4): 128-VGPR cap. (512,8) forced a 64/32-VGPR target
// and the compiler spilled the unrolled window to scratch -> 12 GB/dispatch
// scratch traffic, 3.8 ms (round-5 counters). ~50 live VGPRs need the 128 cap.

#define LROW   (1 << 20)
#define NBATCH 16
#define TBLK   4096
#define NTH    512
#define PWORDS (TBLK + 96)   // staged p words: global t0 .. t0+4191
#define NSLOT  32
#define SLOTW  128           // ws layout: [slot][1..96]=C(s), [100]=pp, [101]=qq

__global__ __launch_bounds__(NTH, 4)
void corr_kernel(const float* __restrict__ P, const float* __restrict__ Q,
                 float* __restrict__ ws) {
    __shared__ float ldsP[PWORDS];
    __shared__ float red[96];
    __shared__ float redp[8];

    const int b    = blockIdx.x >> 8;
    const int tile = blockIdx.x & 255;
    const int t0   = tile * TBLK;
    const float* prow = P + (size_t)b * LROW;
    const float* qrow = Q + (size_t)b * LROW;
    const int tid = threadIdx.x;

    // ---- stage p[t0 .. t0+4191] -> LDS (stride-1 float4), fused TotPP partial ----
    float pp = 0.f;
    for (int k = tid; k < PWORDS / 4; k += NTH) {
        const int gbase = t0 + 4 * k;
        float4 v;
        if (gbase + 3 < LROW) {
            v = *reinterpret_cast<const float4*>(prow + gbase);
        } else {
            v.x = (gbase + 0 < LROW) ? prow[gbase + 0] : 0.f;
            v.y = (gbase + 1 < LROW) ? prow[gbase + 1] : 0.f;
            v.z = (gbase + 2 < LROW) ? prow[gbase + 2] : 0.f;
            v.w = (gbase + 3 < LROW) ? prow[gbase + 3] : 0.f;
        }
        *reinterpret_cast<float4*>(&ldsP[4 * k]) = v;
        if (k < TBLK / 4)   // pp over exactly [t0, t0+4096)
            pp = fmaf(v.x, v.x, fmaf(v.y, v.y, fmaf(v.z, v.z, fmaf(v.w, v.w, pp))));
    }
    __syncthreads();

    const int w  = tid >> 6;        // wave = shift class, s = 1+12w+j
    const int l  = tid & 63;
    const int sb = 12 * w;
    const int lw = 4 * l;

    float acc[12];
    #pragma unroll
    for (int j = 0; j < 12; ++j) acc[j] = 0.f;
    float qq = 0.f;

    for (int sc = 0; sc < 16; ++sc) {
        const int tb = sc * 256;

        // q: one stride-1-coalesced float4 load per lane
        const float4 q0 = *reinterpret_cast<const float4*>(qrow + t0 + tb + lw);

        // p window: 4x stride-1 ds_read_b128 across lanes, i0 mult of 4
        const int i0 = tb + lw + sb;
        const float4 W0 = *reinterpret_cast<const float4*>(&ldsP[i0 +  0]);
        const float4 W1 = *reinterpret_cast<const float4*>(&ldsP[i0 +  4]);
        const float4 W2 = *reinterpret_cast<const float4*>(&ldsP[i0 +  8]);
        const float4 W3 = *reinterpret_cast<const float4*>(&ldsP[i0 + 12]);

        if (w == 0) {   // TotQQ once (wave-uniform branch)
            qq = fmaf(q0.x, q0.x, fmaf(q0.y, q0.y, fmaf(q0.z, q0.z, fmaf(q0.w, q0.w, qq))));
        }

        const float wa[16] = {W0.x,W0.y,W0.z,W0.w, W1.x,W1.y,W1.z,W1.w,
                              W2.x,W2.y,W2.z,W2.w, W3.x,W3.y,W3.z,W3.w};
        const float qa[4] = {q0.x, q0.y, q0.z, q0.w};

        // p global idx = t0 + (tb+lw+r) + s,  s = 1+sb+j  -> lds idx i0 + j+r+1
        #pragma unroll
        for (int j = 0; j < 12; ++j) {
            float a = acc[j];
            #pragma unroll
            for (int r = 0; r < 4; ++r) a = fmaf(wa[j + r + 1], qa[r], a);
            acc[j] = a;
        }
    }

    // ---- reductions: full 64-lane butterflies ----
    #pragma unroll
    for (int j = 0; j < 12; ++j) {
        float v = acc[j];
        v += __shfl_xor(v, 1);  v += __shfl_xor(v, 2);  v += __shfl_xor(v, 4);
        v += __shfl_xor(v, 8);  v += __shfl_xor(v, 16); v += __shfl_xor(v, 32);
        if (l == 0) red[sb + j] = v;
    }
    {
        float v = pp;
        v += __shfl_xor(v, 1);  v += __shfl_xor(v, 2);  v += __shfl_xor(v, 4);
        v += __shfl_xor(v, 8);  v += __shfl_xor(v, 16); v += __shfl_xor(v, 32);
        if (l == 0) redp[w] = v;
    }
    if (w == 0) {
        float v = qq;
        v += __shfl_xor(v, 1);  v += __shfl_xor(v, 2);  v += __shfl_xor(v, 4);
        v += __shfl_xor(v, 8);  v += __shfl_xor(v, 16); v += __shfl_xor(v, 32);
        qq = v;                 // lane 0 holds tile TotQQ
    }
    __syncthreads();

    float* srow = ws + (size_t)(blockIdx.x & (NSLOT - 1)) * SLOTW;
    if (tid < 96) {
        atomicAdd(&srow[1 + tid], red[tid]);
    } else if (tid == 96) {
        float s = 0.f;
        #pragma unroll
        for (int k = 0; k < 8; ++k) s += redp[k];
        atomicAdd(&srow[100], s);
    }
    if (tid == 0) atomicAdd(&srow[101], qq);
}

__global__ void minloss_kernel(const float* __restrict__ P, const float* __restrict__ Q,
                               const float* __restrict__ ws, float* __restrict__ out) {
    __shared__ float hp[96], tq[96], lossbuf[96];
    __shared__ float tots[2];
    const int tid = threadIdx.x;   // 128 threads
    if (tid < 95) {
        float s1 = 0.f, s2 = 0.f;
        #pragma unroll
        for (int b = 0; b < NBATCH; ++b) {
            const float pv = P[(size_t)b * LROW + tid];
            s1 = fmaf(pv, pv, s1);
            const float qv = Q[(size_t)b * LROW + (LROW - 1 - tid)];
            s2 = fmaf(qv, qv, s2);
        }
        hp[tid] = s1;   // sum_b p[u=tid]^2
        tq[tid] = s2;   // sum_b q[L-1-tid]^2
    } else if (tid == 96) {
        float s = 0.f;
        for (int k = 0; k < NSLOT; ++k) s += ws[k * SLOTW + 100];
        tots[0] = s;    // TotPP
    } else if (tid == 97) {
        float s = 0.f;
        for (int k = 0; k < NSLOT; ++k) s += ws[k * SLOTW + 101];
        tots[1] = s;    // TotQQ
    }
    __syncthreads();
    if (tid >= 1 && tid <= 95) {
        float C = 0.f;
        for (int k = 0; k < NSLOT; ++k) C += ws[k * SLOTW + tid];
        float head = 0.f, tail = 0.f;
        for (int u = 0; u < tid; ++u) { head += hp[u]; tail += tq[u]; }
        const float num = (tots[0] - head) + (tots[1] - tail) - 2.f * C;
        lossbuf[tid] = num / (16.f * (float)(LROW - tid));
    }
    __syncthreads();
    if (tid == 0) {
        float m = lossbuf[1];
        for (int s = 2; s <= 95; ++s) m = fminf(m, lossbuf[s]);
        out[0] = m;
    }
}

extern "C" void kernel_launch(void* const* d_in, const int* in_sizes, int n_in,
                              void* d_out, int out_size, void* d_ws, size_t ws_size,
                              hipStream_t stream) {
    const float* P = (const float*)d_in[0];   // predict
    const float* Q = (const float*)d_in[1];   // target
    float* ws = (float*)d_ws;

    hipMemsetAsync(d_ws, 0, NSLOT * SLOTW * sizeof(float), stream);
    corr_kernel<<<NBATCH * (LROW / TBLK), NTH, 0, stream>>>(P, Q, ws);
    minloss_kernel<<<1, 128, 0, stream>>>(P, Q, ws, (float*)d_out);
}

// Round 8
// 2671.349 us; speedup vs baseline: 1.4498x; 1.0048x over previous
//
#include <hip/hip_runtime.h>

// OffsetMSE: min over s in [1,95] of  sum_b sum_{t<L-s} (p[b,t+s]-q[b,t])^2 / (B*(L-s))
// num(s) = (TotPP - HeadPP(s)) + (TotQQ - TailQQ(s)) - 2*C(s),
// C(s) = sum_b sum_t p_pad[t+s]*q[t]   (1 FMA per element, zero-pad handles mask).
//
// Layout: 4096 blocks (16 batches x 256 t-tiles of 4096), 512 threads = 8 waves.
// Wave w owns shifts s = 1+12w .. 12+12w; lane owns 4 t-words per sub-chunk.
// All LDS reads and global q reads are stride-1 across lanes (conflict-free,
// fully coalesced). pp computed during staging (P read exactly once).
//
// NO __launch_bounds__: empirically (rounds 5/6) hipcc treats the 2nd arg as
// blocks-per-CU (CUDA semantics); (512,8)->32 VGPR cap and (512,4)->64 cap both
// forced the ~75-VGPR live set to scratch (3.7-5 GB HBM writes/dispatch, ~3 ms).
// Unbounded, the allocator picks what it needs; 4096 blocks provide the TLP.

#define LROW   (1 << 20)
#define NBATCH 16
#define TBLK   4096
#define NTH    512
#define PWORDS (TBLK + 96)   // staged p words: global t0 .. t0+4191
#define NSLOT  32
#define SLOTW  128           // ws layout: [slot][1..96]=C(s), [100]=pp, [101]=qq

__global__
void corr_kernel(const float* __restrict__ P, const float* __restrict__ Q,
                 float* __restrict__ ws) {
    __shared__ float ldsP[PWORDS];
    __shared__ float red[96];
    __shared__ float redp[8];

    const int b    = blockIdx.x >> 8;
    const int tile = blockIdx.x & 255;
    const int t0   = tile * TBLK;
    const float* prow = P + (size_t)b * LROW;
    const float* qrow = Q + (size_t)b * LROW;
    const int tid = threadIdx.x;

    // ---- stage p[t0 .. t0+4191] -> LDS (stride-1 float4), fused TotPP partial ----
    float pp = 0.f;
    for (int k = tid; k < PWORDS / 4; k += NTH) {
        const int gbase = t0 + 4 * k;
        float4 v;
        if (gbase + 3 < LROW) {
            v = *reinterpret_cast<const float4*>(prow + gbase);
        } else {
            v.x = (gbase + 0 < LROW) ? prow[gbase + 0] : 0.f;
            v.y = (gbase + 1 < LROW) ? prow[gbase + 1] : 0.f;
            v.z = (gbase + 2 < LROW) ? prow[gbase + 2] : 0.f;
            v.w = (gbase + 3 < LROW) ? prow[gbase + 3] : 0.f;
        }
        *reinterpret_cast<float4*>(&ldsP[4 * k]) = v;
        if (k < TBLK / 4)   // pp over exactly [t0, t0+4096)
            pp = fmaf(v.x, v.x, fmaf(v.y, v.y, fmaf(v.z, v.z, fmaf(v.w, v.w, pp))));
    }
    __syncthreads();

    const int w  = tid >> 6;        // wave = shift class, s = 1+12w+j
    const int l  = tid & 63;
    const int sb = 12 * w;
    const int lw = 4 * l;

    float acc[12];
    #pragma unroll
    for (int j = 0; j < 12; ++j) acc[j] = 0.f;
    float qq = 0.f;

    for (int sc = 0; sc < 16; ++sc) {
        const int tb = sc * 256;

        // q: one stride-1-coalesced float4 load per lane
        const float4 q0 = *reinterpret_cast<const float4*>(qrow + t0 + tb + lw);

        // p window: 4x stride-1 ds_read_b128 across lanes, i0 mult of 4
        const int i0 = tb + lw + sb;
        const float4 W0 = *reinterpret_cast<const float4*>(&ldsP[i0 +  0]);
        const float4 W1 = *reinterpret_cast<const float4*>(&ldsP[i0 +  4]);
        const float4 W2 = *reinterpret_cast<const float4*>(&ldsP[i0 +  8]);
        const float4 W3 = *reinterpret_cast<const float4*>(&ldsP[i0 + 12]);

        if (w == 0) {   // TotQQ once (wave-uniform branch)
            qq = fmaf(q0.x, q0.x, fmaf(q0.y, q0.y, fmaf(q0.z, q0.z, fmaf(q0.w, q0.w, qq))));
        }

        const float wa[16] = {W0.x,W0.y,W0.z,W0.w, W1.x,W1.y,W1.z,W1.w,
                              W2.x,W2.y,W2.z,W2.w, W3.x,W3.y,W3.z,W3.w};
        const float qa[4] = {q0.x, q0.y, q0.z, q0.w};

        // p global idx = t0 + (tb+lw+r) + s,  s = 1+sb+j  -> lds idx i0 + j+r+1
        #pragma unroll
        for (int j = 0; j < 12; ++j) {
            float a = acc[j];
            #pragma unroll
            for (int r = 0; r < 4; ++r) a = fmaf(wa[j + r + 1], qa[r], a);
            acc[j] = a;
        }
    }

    // ---- reductions: full 64-lane butterflies ----
    #pragma unroll
    for (int j = 0; j < 12; ++j) {
        float v = acc[j];
        v += __shfl_xor(v, 1);  v += __shfl_xor(v, 2);  v += __shfl_xor(v, 4);
        v += __shfl_xor(v, 8);  v += __shfl_xor(v, 16); v += __shfl_xor(v, 32);
        if (l == 0) red[sb + j] = v;
    }
    {
        float v = pp;
        v += __shfl_xor(v, 1);  v += __shfl_xor(v, 2);  v += __shfl_xor(v, 4);
        v += __shfl_xor(v, 8);  v += __shfl_xor(v, 16); v += __shfl_xor(v, 32);
        if (l == 0) redp[w] = v;
    }
    if (w == 0) {
        float v = qq;
        v += __shfl_xor(v, 1);  v += __shfl_xor(v, 2);  v += __shfl_xor(v, 4);
        v += __shfl_xor(v, 8);  v += __shfl_xor(v, 16); v += __shfl_xor(v, 32);
        qq = v;                 // lane 0 holds tile TotQQ
    }
    __syncthreads();

    float* srow = ws + (size_t)(blockIdx.x & (NSLOT - 1)) * SLOTW;
    if (tid < 96) {
        atomicAdd(&srow[1 + tid], red[tid]);
    } else if (tid == 96) {
        float s = 0.f;
        #pragma unroll
        for (int k = 0; k < 8; ++k) s += redp[k];
        atomicAdd(&srow[100], s);
    }
    if (tid == 0) atomicAdd(&srow[101], qq);
}

__global__ void minloss_kernel(const float* __restrict__ P, const float* __restrict__ Q,
                               const float* __restrict__ ws, float* __restrict__ out) {
    __shared__ float hp[96], tq[96], lossbuf[96];
    __shared__ float tots[2];
    const int tid = threadIdx.x;   // 128 threads
    if (tid < 95) {
        float s1 = 0.f, s2 = 0.f;
        #pragma unroll
        for (int b = 0; b < NBATCH; ++b) {
            const float pv = P[(size_t)b * LROW + tid];
            s1 = fmaf(pv, pv, s1);
            const float qv = Q[(size_t)b * LROW + (LROW - 1 - tid)];
            s2 = fmaf(qv, qv, s2);
        }
        hp[tid] = s1;   // sum_b p[u=tid]^2
        tq[tid] = s2;   // sum_b q[L-1-tid]^2
    } else if (tid == 96) {
        float s = 0.f;
        for (int k = 0; k < NSLOT; ++k) s += ws[k * SLOTW + 100];
        tots[0] = s;    // TotPP
    } else if (tid == 97) {
        float s = 0.f;
        for (int k = 0; k < NSLOT; ++k) s += ws[k * SLOTW + 101];
        tots[1] = s;    // TotQQ
    }
    __syncthreads();
    if (tid >= 1 && tid <= 95) {
        float C = 0.f;
        for (int k = 0; k < NSLOT; ++k) C += ws[k * SLOTW + tid];
        float head = 0.f, tail = 0.f;
        for (int u = 0; u < tid; ++u) { head += hp[u]; tail += tq[u]; }
        const float num = (tots[0] - head) + (tots[1] - tail) - 2.f * C;
        lossbuf[tid] = num / (16.f * (float)(LROW - tid));
    }
    __syncthreads();
    if (tid == 0) {
        float m = lossbuf[1];
        for (int s = 2; s <= 95; ++s) m = fminf(m, lossbuf[s]);
        out[0] = m;
    }
}

extern "C" void kernel_launch(void* const* d_in, const int* in_sizes, int n_in,
                              void* d_out, int out_size, void* d_ws, size_t ws_size,
                              hipStream_t stream) {
    const float* P = (const float*)d_in[0];   // predict
    const float* Q = (const float*)d_in[1];   // target
    float* ws = (float*)d_ws;

    hipMemsetAsync(d_ws, 0, NSLOT * SLOTW * sizeof(float), stream);
    corr_kernel<<<NBATCH * (LROW / TBLK), NTH, 0, stream>>>(P, Q, ws);
    minloss_kernel<<<1, 128, 0, stream>>>(P, Q, ws, (float*)d_out);
}